// Round 2
// baseline (483.966 us; speedup 1.0000x reference)
//
#include <hip/hip_runtime.h>
#include <hip/hip_bf16.h>

#define ALPHA 0.05f

constexpr int FULL = 4096;   // full in/out dim
constexpr int Mtot = 8192;   // B*S = 4*2048
constexpr int Kc   = 2048;   // N_COLS (active input channels)
constexpr int Nc   = 2048;   // N_ROWS (active output channels)

typedef __hip_bfloat16 bf16_t;
using bf16x8 = __attribute__((ext_vector_type(8))) __bf16;
using f32x4  = __attribute__((ext_vector_type(4))) float;

__device__ __forceinline__ void gload_lds16(const bf16_t* g, bf16_t* l) {
  __builtin_amdgcn_global_load_lds(
      (const __attribute__((address_space(1))) void*)g,
      (__attribute__((address_space(3))) void*)l, 16, 0, 0);
}

// ---------- gather active cols of x and convert to bf16: A[Mtot][Kc] ----------
__global__ void k_convert_x(const float* __restrict__ x,
                            const int* __restrict__ cols,
                            bf16_t* __restrict__ A) {
  int idx = blockIdx.x * blockDim.x + threadIdx.x;  // Mtot * Kc/8 threads
  int m  = idx >> 8;                                // Kc/8 = 256
  int k8 = (idx & 255) << 3;
  const float* xr = x + (size_t)m * FULL;
  bf16_t tmp[8];
#pragma unroll
  for (int j = 0; j < 8; ++j) tmp[j] = __float2bfloat16(xr[cols[k8 + j]]);
  *reinterpret_cast<uint4*>(&A[(size_t)m * Kc + k8]) =
      *reinterpret_cast<const uint4*>(tmp);
}

// ---------- convert ALPHA*W to bf16: Wb[Nc][Kc] (row-major == B^T layout) ----------
__global__ void k_convert_w(const float* __restrict__ w, bf16_t* __restrict__ Wb) {
  int idx = blockIdx.x * blockDim.x + threadIdx.x;  // Nc*Kc/8 threads
  const float4* src = reinterpret_cast<const float4*>(w) + (size_t)idx * 2;
  float4 v0 = src[0], v1 = src[1];
  bf16_t tmp[8];
  tmp[0] = __float2bfloat16(v0.x * ALPHA);
  tmp[1] = __float2bfloat16(v0.y * ALPHA);
  tmp[2] = __float2bfloat16(v0.z * ALPHA);
  tmp[3] = __float2bfloat16(v0.w * ALPHA);
  tmp[4] = __float2bfloat16(v1.x * ALPHA);
  tmp[5] = __float2bfloat16(v1.y * ALPHA);
  tmp[6] = __float2bfloat16(v1.z * ALPHA);
  tmp[7] = __float2bfloat16(v1.w * ALPHA);
  *reinterpret_cast<uint4*>(&Wb[(size_t)idx * 8]) =
      *reinterpret_cast<const uint4*>(tmp);
}

// ---------- fill full output with broadcast bias ----------
__global__ void k_bias_fill(const float* __restrict__ bias, float* __restrict__ out) {
  int idx = blockIdx.x * blockDim.x + threadIdx.x;  // Mtot*FULL/4 threads
  const float4 v = reinterpret_cast<const float4*>(bias)[idx & 1023];  // FULL/4=1024
  reinterpret_cast<float4*>(out)[idx] = v;
}

// ---------- m97-style bf16 MFMA GEMM with scatter epilogue ----------
constexpr int BM = 128, BN = 128, BK = 64;
constexpr int GRID_N = Nc / BN;          // 16
constexpr int GRID_M = Mtot / BM;        // 64
constexpr int NWG    = GRID_N * GRID_M;  // 1024 (divisible by 8 -> simple swizzle ok)

__global__ __launch_bounds__(256)
void k_gemm(const bf16_t* __restrict__ A,   // [Mtot][Kc]
            const bf16_t* __restrict__ Wb,  // [Nc][Kc]
            const float* __restrict__ bias,
            const int* __restrict__ rows,
            float* __restrict__ out) {
  __shared__ __align__(16) bf16_t As[BM * BK];
  __shared__ __align__(16) bf16_t Bs[BN * BK];

  // T1: bijective XCD swizzle (NWG % 8 == 0). Consecutive intra-XCD ids
  // share the A row-panel (bn varies fastest) -> per-XCD L2 locality.
  const int bid = blockIdx.x;
  const int wgid = (bid & 7) * (NWG / 8) + (bid >> 3);
  const int bm0 = (wgid / GRID_N) * BM;
  const int bn0 = (wgid % GRID_N) * BN;

  const int t = threadIdx.x;
  const int w = t >> 6, l = t & 63;
  const int wm = (w >> 1) * 64, wn = (w & 1) * 64;

  // staging geometry: instr i stages tile elements [i*2048, i*2048+2048),
  // thread t covers 8 bf16 at elem = i*2048 + t*8; row = elem/64, col = elem%64
  const bf16_t* srcA[4];
  const bf16_t* srcB[4];
#pragma unroll
  for (int i = 0; i < 4; ++i) {
    int elem = i * 2048 + t * 8;
    int row = elem >> 6, col = elem & 63;
    srcA[i] = A  + (size_t)(bm0 + row) * Kc + col;
    srcB[i] = Wb + (size_t)(bn0 + row) * Kc + col;
  }

  f32x4 acc[4][4] = {};

  for (int k0 = 0; k0 < Kc; k0 += BK) {
#pragma unroll
    for (int i = 0; i < 4; ++i) {
      // LDS dest is wave-uniform base + lane*16 (HW rule); per-lane global src
      gload_lds16(srcA[i] + k0, As + i * 2048 + w * 512);
      gload_lds16(srcB[i] + k0, Bs + i * 2048 + w * 512);
    }
    __syncthreads();   // drains vmcnt -> tiles ready

    const int r = l & 15;
#pragma unroll
    for (int kk = 0; kk < 2; ++kk) {
      const int ko = kk * 32 + (l >> 4) * 8;
      bf16x8 af[4], bf[4];
#pragma unroll
      for (int mi = 0; mi < 4; ++mi)
        af[mi] = *reinterpret_cast<const bf16x8*>(&As[(wm + mi * 16 + r) * BK + ko]);
#pragma unroll
      for (int ni = 0; ni < 4; ++ni)
        bf[ni] = *reinterpret_cast<const bf16x8*>(&Bs[(wn + ni * 16 + r) * BK + ko]);
#pragma unroll
      for (int mi = 0; mi < 4; ++mi)
#pragma unroll
        for (int ni = 0; ni < 4; ++ni)
          acc[mi][ni] = __builtin_amdgcn_mfma_f32_16x16x32_bf16(
              af[mi], bf[ni], acc[mi][ni], 0, 0, 0);
    }
    __syncthreads();   // compute done before next stage overwrites
  }

  // epilogue: C/D layout col = lane&15, row = (lane>>4)*4 + j  [m89/m91-verified]
  const int lr = (l >> 4) * 4, lc = l & 15;
#pragma unroll
  for (int ni = 0; ni < 4; ++ni) {
    int ncomp = bn0 + wn + ni * 16 + lc;
    int oc = rows[ncomp];
    float bv = bias[oc];
#pragma unroll
    for (int mi = 0; mi < 4; ++mi) {
#pragma unroll
      for (int j = 0; j < 4; ++j) {
        int m = bm0 + wm + mi * 16 + lr + j;
        out[(size_t)m * FULL + oc] = acc[mi][ni][j] + bv;
      }
    }
  }
}

// ---------- fallback (only if ws_size too small): correct but slow ----------
__global__ void k_gemm_naive(const float* __restrict__ x, const float* __restrict__ wgt,
                             const float* __restrict__ bias, const int* __restrict__ rows,
                             const int* __restrict__ cols, float* __restrict__ out) {
  int idx = blockIdx.x * blockDim.x + threadIdx.x;  // Mtot*Nc
  int m = idx / Nc, n = idx - (idx / Nc) * Nc;
  const float* xr = x + (size_t)m * FULL;
  const float* wr = wgt + (size_t)n * Kc;
  float s = 0.f;
  for (int k = 0; k < Kc; ++k) s += xr[cols[k]] * wr[k];
  int oc = rows[n];
  out[(size_t)m * FULL + oc] = s * ALPHA + bias[oc];
}

extern "C" void kernel_launch(void* const* d_in, const int* in_sizes, int n_in,
                              void* d_out, int out_size, void* d_ws, size_t ws_size,
                              hipStream_t stream) {
  const float* x    = (const float*)d_in[0];
  const float* wgt  = (const float*)d_in[1];
  const float* bias = (const float*)d_in[2];
  const int*   rows = (const int*)d_in[3];
  const int*   cols = (const int*)d_in[4];
  float* out = (float*)d_out;

  const size_t needA = (size_t)Mtot * Kc * sizeof(bf16_t);  // 32 MiB
  const size_t needW = (size_t)Nc * Kc * sizeof(bf16_t);    //  8 MiB

  if (ws_size >= needA + needW) {
    bf16_t* Abf = (bf16_t*)d_ws;
    bf16_t* Wbf = (bf16_t*)((char*)d_ws + needA);
    k_convert_x<<<(Mtot * (Kc / 8)) / 256, 256, 0, stream>>>(x, cols, Abf);
    k_convert_w<<<(Nc * (Kc / 8)) / 256, 256, 0, stream>>>(wgt, Wbf);
    k_bias_fill<<<(Mtot * (FULL / 4)) / 256, 256, 0, stream>>>(bias, out);
    k_gemm<<<NWG, 256, 0, stream>>>(Abf, Wbf, bias, rows, out);
  } else {
    k_bias_fill<<<(Mtot * (FULL / 4)) / 256, 256, 0, stream>>>(bias, out);
    k_gemm_naive<<<(Mtot * Nc) / 256, 256, 0, stream>>>(x, wgt, bias, rows, cols, out);
  }
}

// Round 4
// 359.175 us; speedup vs baseline: 1.3474x; 1.3474x over previous
//
#include <hip/hip_runtime.h>
#include <hip/hip_bf16.h>

#define ALPHA 0.05f

constexpr int FULL = 4096;   // full in/out dim
constexpr int Mtot = 8192;   // B*S
constexpr int Kc   = 2048;   // active input channels
constexpr int Nc   = 2048;   // active output channels

typedef __hip_bfloat16 bf16_t;
using bf16x8 = __attribute__((ext_vector_type(8))) __bf16;
using f32x4  = __attribute__((ext_vector_type(4))) float;

__device__ __forceinline__ void gload_lds16(const bf16_t* g, bf16_t* l) {
  __builtin_amdgcn_global_load_lds(
      (const __attribute__((address_space(1))) void*)g,
      (__attribute__((address_space(3))) void*)l, 16, 0, 0);
}

// ---------- gather active cols of x -> bf16 A[Mtot][Kc], LDS-staged ----------
__global__ __launch_bounds__(256)
void k_convert_x(const float* __restrict__ x, const int* __restrict__ cols,
                 bf16_t* __restrict__ A) {
  __shared__ float xr[FULL];
  const int m = blockIdx.x, t = threadIdx.x;
  const float4* xg = reinterpret_cast<const float4*>(x + (size_t)m * FULL);
  float4* xl = reinterpret_cast<float4*>(xr);
#pragma unroll
  for (int i = 0; i < FULL / 1024; ++i) xl[t + i * 256] = xg[t + i * 256];
  __syncthreads();
  const int4 c0 = reinterpret_cast<const int4*>(cols)[t * 2];      // L2-resident
  const int4 c1 = reinterpret_cast<const int4*>(cols)[t * 2 + 1];
  bf16_t tmp[8];
  tmp[0] = __float2bfloat16(xr[c0.x]);
  tmp[1] = __float2bfloat16(xr[c0.y]);
  tmp[2] = __float2bfloat16(xr[c0.z]);
  tmp[3] = __float2bfloat16(xr[c0.w]);
  tmp[4] = __float2bfloat16(xr[c1.x]);
  tmp[5] = __float2bfloat16(xr[c1.y]);
  tmp[6] = __float2bfloat16(xr[c1.z]);
  tmp[7] = __float2bfloat16(xr[c1.w]);
  reinterpret_cast<uint4*>(A + (size_t)m * Kc)[t] =
      *reinterpret_cast<const uint4*>(tmp);
}

// ---------- ALPHA*W -> bf16 Wb[Nc][Kc] ----------
__global__ void k_convert_w(const float* __restrict__ w, bf16_t* __restrict__ Wb) {
  int idx = blockIdx.x * blockDim.x + threadIdx.x;
  const float4* src = reinterpret_cast<const float4*>(w) + (size_t)idx * 2;
  float4 v0 = src[0], v1 = src[1];
  bf16_t tmp[8];
  tmp[0] = __float2bfloat16(v0.x * ALPHA);
  tmp[1] = __float2bfloat16(v0.y * ALPHA);
  tmp[2] = __float2bfloat16(v0.z * ALPHA);
  tmp[3] = __float2bfloat16(v0.w * ALPHA);
  tmp[4] = __float2bfloat16(v1.x * ALPHA);
  tmp[5] = __float2bfloat16(v1.y * ALPHA);
  tmp[6] = __float2bfloat16(v1.z * ALPHA);
  tmp[7] = __float2bfloat16(v1.w * ALPHA);
  *reinterpret_cast<uint4*>(&Wb[(size_t)idx * 8]) =
      *reinterpret_cast<const uint4*>(tmp);
}

// ---------- bias fill (fallback path only) ----------
__global__ void k_bias_fill(const float* __restrict__ bias, float* __restrict__ out) {
  int idx = blockIdx.x * blockDim.x + threadIdx.x;
  const float4 v = reinterpret_cast<const float4*>(bias)[idx & (FULL / 4 - 1)];
  reinterpret_cast<float4*>(out)[idx] = v;
}

// ---------- m97-style bf16 MFMA GEMM ----------
constexpr int BM = 128, BN = 128, BK = 64;
constexpr int GRID_N = Nc / BN;          // 16
constexpr int GRID_M = Mtot / BM;        // 64
constexpr int NWG    = GRID_N * GRID_M;  // 1024

template <bool COMPACT>
__global__ __launch_bounds__(256)
void k_gemm(const bf16_t* __restrict__ A, const bf16_t* __restrict__ Wb,
            const float* __restrict__ bias, const int* __restrict__ rows,
            float* __restrict__ out) {
  __shared__ __align__(16) bf16_t As[BM * BK];
  __shared__ __align__(16) bf16_t Bs[BN * BK];

  // Supertile XCD swizzle: XCD = bid%8 (dispatch heuristic). Each XCD owns an
  // 8(bm)x16(bn) region, processed as 2x4 supertiles of 4x4 blocks:
  // concurrent working set ~4 A-panels + 4 B-panels = 4 MiB ~= per-XCD L2.
  const int bid = blockIdx.x;
  const int xcd = bid & 7, lid = bid >> 3;       // lid in [0,128)
  const int st = lid >> 4, wi = lid & 15;        // supertile / within
  const int st_r = st >> 2, st_c = st & 3;       // 2 x 4 supertiles
  const int ir = wi >> 2, ic = wi & 3;           // 4 x 4 blocks
  const int bm0 = (xcd * 8 + st_r * 4 + ir) * BM;
  const int bn0 = (st_c * 4 + ic) * BN;

  const int t = threadIdx.x;
  const int w = t >> 6, l = t & 63;
  const int wm = (w >> 1) * 64, wn = (w & 1) * 64;

  const bf16_t* srcA[4];
  const bf16_t* srcB[4];
#pragma unroll
  for (int i = 0; i < 4; ++i) {
    int elem = i * 2048 + t * 8;
    int row = elem >> 6, col = elem & 63;
    srcA[i] = A  + (size_t)(bm0 + row) * Kc + col;
    srcB[i] = Wb + (size_t)(bn0 + row) * Kc + col;
  }

  f32x4 acc[4][4] = {};

  for (int k0 = 0; k0 < Kc; k0 += BK) {
#pragma unroll
    for (int i = 0; i < 4; ++i) {
      gload_lds16(srcA[i] + k0, As + i * 2048 + w * 512);
      gload_lds16(srcB[i] + k0, Bs + i * 2048 + w * 512);
    }
    __syncthreads();

    const int r = l & 15;
#pragma unroll
    for (int kk = 0; kk < 2; ++kk) {
      const int ko = kk * 32 + (l >> 4) * 8;
      bf16x8 af[4], bf[4];
#pragma unroll
      for (int mi = 0; mi < 4; ++mi)
        af[mi] = *reinterpret_cast<const bf16x8*>(&As[(wm + mi * 16 + r) * BK + ko]);
#pragma unroll
      for (int ni = 0; ni < 4; ++ni)
        bf[ni] = *reinterpret_cast<const bf16x8*>(&Bs[(wn + ni * 16 + r) * BK + ko]);
#pragma unroll
      for (int mi = 0; mi < 4; ++mi)
#pragma unroll
        for (int ni = 0; ni < 4; ++ni)
          acc[mi][ni] = __builtin_amdgcn_mfma_f32_16x16x32_bf16(
              af[mi], bf[ni], acc[mi][ni], 0, 0, 0);
    }
    __syncthreads();
  }

  // C/D layout: col = lane&15, row = (lane>>4)*4 + j  [m89/m91-verified]
  const int lr = (l >> 4) * 4, lc = l & 15;
  if (COMPACT) {
#pragma unroll
    for (int ni = 0; ni < 4; ++ni) {
      int nc = bn0 + wn + ni * 16 + lc;
#pragma unroll
      for (int mi = 0; mi < 4; ++mi)
#pragma unroll
        for (int j = 0; j < 4; ++j)
          out[(size_t)(bm0 + wm + mi * 16 + lr + j) * Nc + nc] = acc[mi][ni][j];
    }
  } else {
#pragma unroll
    for (int ni = 0; ni < 4; ++ni) {
      int nc = bn0 + wn + ni * 16 + lc;
      int oc = rows[nc];
      float bv = bias[oc];
#pragma unroll
      for (int mi = 0; mi < 4; ++mi)
#pragma unroll
        for (int j = 0; j < 4; ++j)
          out[(size_t)(bm0 + wm + mi * 16 + lr + j) * FULL + oc] =
              acc[mi][ni][j] + bv;
    }
  }
}

// ---------- fused zero-scatter + bias: out[m][:] = scatter(yc[m]) + bias ----------
__global__ __launch_bounds__(256)
void k_output(const float* __restrict__ yc, const float* __restrict__ bias,
              const int* __restrict__ rows, float* __restrict__ out) {
  __shared__ float row[FULL];
  const int m = blockIdx.x, t = threadIdx.x;
  const float4 z4 = {0.f, 0.f, 0.f, 0.f};
  float4* rl = reinterpret_cast<float4*>(row);
#pragma unroll
  for (int i = 0; i < FULL / 1024; ++i) rl[t + i * 256] = z4;
  __syncthreads();
  const float4* ycr = reinterpret_cast<const float4*>(yc + (size_t)m * Nc);
#pragma unroll
  for (int i = 0; i < Nc / 1024; ++i) {
    int idx = t + i * 256;
    float4 v = ycr[idx];                                   // coalesced
    int4 rr = reinterpret_cast<const int4*>(rows)[idx];    // L2-resident
    row[rr.x] = v.x;
    row[rr.y] = v.y;
    row[rr.z] = v.z;
    row[rr.w] = v.w;
  }
  __syncthreads();
  float4* orow = reinterpret_cast<float4*>(out + (size_t)m * FULL);
  const float4* b4 = reinterpret_cast<const float4*>(bias);
#pragma unroll
  for (int i = 0; i < FULL / 1024; ++i) {
    int idx = t + i * 256;
    float4 r = rl[idx];
    float4 b = b4[idx];
    r.x += b.x; r.y += b.y; r.z += b.z; r.w += b.w;
    orow[idx] = r;                                         // coalesced
  }
}

// ---------- naive fallback ----------
__global__ void k_gemm_naive(const float* __restrict__ x, const float* __restrict__ wgt,
                             const float* __restrict__ bias, const int* __restrict__ rows,
                             const int* __restrict__ cols, float* __restrict__ out) {
  int idx = blockIdx.x * blockDim.x + threadIdx.x;
  int m = idx / Nc, n = idx - (idx / Nc) * Nc;
  const float* xr = x + (size_t)m * FULL;
  const float* wr = wgt + (size_t)n * Kc;
  float s = 0.f;
  for (int k = 0; k < Kc; ++k) s += xr[cols[k]] * wr[k];
  int oc = rows[n];
  out[(size_t)m * FULL + oc] = s * ALPHA + bias[oc];
}

extern "C" void kernel_launch(void* const* d_in, const int* in_sizes, int n_in,
                              void* d_out, int out_size, void* d_ws, size_t ws_size,
                              hipStream_t stream) {
  const float* x    = (const float*)d_in[0];
  const float* wgt  = (const float*)d_in[1];
  const float* bias = (const float*)d_in[2];
  const int*   rows = (const int*)d_in[3];
  const int*   cols = (const int*)d_in[4];
  float* out = (float*)d_out;

  const size_t needA = (size_t)Mtot * Kc * sizeof(bf16_t);  // 32 MiB
  const size_t needW = (size_t)Nc * Kc * sizeof(bf16_t);    //  8 MiB
  const size_t needY = (size_t)Mtot * Nc * sizeof(float);   // 64 MiB

  if (ws_size >= needA + needW + needY) {
    bf16_t* Abf = (bf16_t*)d_ws;
    bf16_t* Wbf = (bf16_t*)((char*)d_ws + needA);
    float*  yc  = (float*)((char*)d_ws + needA + needW);
    k_convert_x<<<Mtot, 256, 0, stream>>>(x, cols, Abf);
    k_convert_w<<<(Nc * (Kc / 8)) / 256, 256, 0, stream>>>(wgt, Wbf);
    k_gemm<true><<<NWG, 256, 0, stream>>>(Abf, Wbf, nullptr, nullptr, yc);
    k_output<<<Mtot, 256, 0, stream>>>(yc, bias, rows, out);
  } else if (ws_size >= needA + needW) {
    bf16_t* Abf = (bf16_t*)d_ws;
    bf16_t* Wbf = (bf16_t*)((char*)d_ws + needA);
    k_convert_x<<<Mtot, 256, 0, stream>>>(x, cols, Abf);
    k_convert_w<<<(Nc * (Kc / 8)) / 256, 256, 0, stream>>>(wgt, Wbf);
    k_bias_fill<<<(Mtot * (FULL / 4)) / 256, 256, 0, stream>>>(bias, out);
    k_gemm<false><<<NWG, 256, 0, stream>>>(Abf, Wbf, bias, rows, out);
  } else {
    k_bias_fill<<<(Mtot * (FULL / 4)) / 256, 256, 0, stream>>>(bias, out);
    k_gemm_naive<<<(Mtot * Nc) / 256, 256, 0, stream>>>(x, wgt, bias, rows, cols, out);
  }
}